// Round 3
// baseline (910.026 us; speedup 1.0000x reference)
//
#include <hip/hip_runtime.h>
#include <math.h>

typedef unsigned short u16;
typedef __attribute__((ext_vector_type(8))) short short8;
typedef __attribute__((ext_vector_type(8))) unsigned short ushort8;
typedef __attribute__((ext_vector_type(4))) float floatx4;

#define NTOK 4096
#define DDIM 1024
#define FDIM 4096
#define NEXP 8
#define ROWS_PAD 9216   // 8192 + worst-case per-expert 128-padding
#define MTILES 72       // ROWS_PAD / 128
#define G1BLK ((FDIM / 128) * MTILES)          // 2304 gemm1 blocks
#define G2BLK ((DDIM / 128) * MTILES)          // 576 gemm2 blocks
#define TW1 ((FDIM / 64) * (DDIM / 64) * NEXP) // 8192 W1-transpose tiles
#define TW2 ((DDIM / 64) * (FDIM / 64) * NEXP) // 8192 W2-transpose tiles
#define NORMB (NTOK * DDIM / 8 / 256)          // 2048
#define ROUTB (NTOK / 4)                       // 1024

// ---------- bf16 <-> f32 (raw bits, RNE) ----------
__device__ __forceinline__ float b2f(u16 u) {
    union { unsigned u32; float f; } v; v.u32 = ((unsigned)u) << 16; return v.f;
}
__device__ __forceinline__ u16 f2b(float f) {
    union { float f; unsigned u; } v; v.f = f;
    unsigned u = v.u;
    return (u16)((u + 0x7fffu + ((u >> 16) & 1u)) >> 16);
}
__device__ __forceinline__ float bf16r(float f) { return b2f(f2b(f)); }

// async global->LDS, 16B per lane. LDS dest must be wave-uniform base + lane*16.
__device__ __forceinline__ void async16(const u16* g, u16* l) {
    __builtin_amdgcn_global_load_lds((const __attribute__((address_space(1))) void*)g,
                                     (__attribute__((address_space(3))) void*)l,
                                     16, 0, 0);
}

// counted vmcnt wait + raw barrier (never drain to 0 in steady state)
template<int V> __device__ __forceinline__ void waitbar() {
    if constexpr (V == 4)      asm volatile("s_waitcnt vmcnt(4)\ns_barrier" ::: "memory");
    else                       asm volatile("s_waitcnt vmcnt(0)\ns_barrier" ::: "memory");
}

// ---------------- init + dtype probe ------------------------------------------
__global__ __launch_bounds__(256) void init_probe_kernel(const u16* __restrict__ wr,
        int* __restrict__ flag, int* __restrict__ row_token,
        float* __restrict__ row_weight, int* __restrict__ counts16) {
    int i = blockIdx.x * 256 + threadIdx.x;
    if (i < ROWS_PAD) { row_token[i] = 0; row_weight[i] = 0.f; }
    if (i < 16) counts16[i] = 0;   // counts[8] + cursor[8]
    if (blockIdx.x == 0) {
        __shared__ int cnt;
        if (threadIdx.x == 0) cnt = 0;
        __syncthreads();
        int c = 0;
        for (int k = threadIdx.x; k < 8192; k += 256) {
            int e = (wr[k] >> 7) & 0xFF;
            c += (e >= 90 && e <= 130) ? 1 : 0;
        }
        atomicAdd(&cnt, c);
        __syncthreads();
        if (threadIdx.x == 0) *flag = (cnt >= 7400) ? 1 : 0;   // 1 = bf16
    }
}

// ---------------- 64x64 transpose tile (256 threads), device-side -------------
__device__ __forceinline__ void transpose_tile(const void* __restrict__ src,
        u16* __restrict__ dst, int R, int C, int isbf, int e, int bx, int by,
        u16* tile /* 64*66 u16 scratch */) {
    size_t eoff = (size_t)e * R * C;
    int bc = bx * 64;
    int br = by * 64;
    int tid = threadIdx.x;
#pragma unroll
    for (int c = tid; c < 512; c += 256) {
        int r = c >> 3, cc = (c & 7) * 8;
        if (isbf) {
            ushort8 v = *(const ushort8*)((const u16*)src + eoff + (size_t)(br + r) * C + bc + cc);
#pragma unroll
            for (int l = 0; l < 8; ++l) tile[r * 66 + cc + l] = v[l];
        } else {
            const float* s = (const float*)src + eoff + (size_t)(br + r) * C + bc + cc;
            floatx4 a = *(const floatx4*)s;
            floatx4 b = *(const floatx4*)(s + 4);
#pragma unroll
            for (int l = 0; l < 4; ++l) { tile[r * 66 + cc + l] = f2b(a[l]); tile[r * 66 + cc + 4 + l] = f2b(b[l]); }
        }
    }
    __syncthreads();
#pragma unroll
    for (int c = tid; c < 512; c += 256) {
        int i = c >> 3, jj = (c & 7) * 8;
        ushort8 o;
#pragma unroll
        for (int l = 0; l < 8; ++l) o[l] = tile[(jj + l) * 66 + i];
        *(ushort8*)(dst + eoff + (size_t)(bc + i) * R + br + jj) = o;
    }
}

// ---------------- prep: W1 transpose + normx + router in one launch -----------
__global__ __launch_bounds__(256) void prep_kernel(const void* __restrict__ W1,
        u16* __restrict__ WT1, const void* __restrict__ x, u16* __restrict__ xb,
        const void* __restrict__ wrr, const int* __restrict__ flag,
        int* __restrict__ tok_e, float* __restrict__ tok_w, int* __restrict__ counts) {
    __shared__ u16 tile[64 * 66];
    int b = blockIdx.x;
    const int isbf = *flag;
    if (b < TW1) {   // ---- W1 [D][F] -> WT1 [F][D], per expert
        int e = b >> 10, rem = b & 1023;
        int bx = rem & 63, by = rem >> 6;   // C=FDIM (64 tiles), R=DDIM (16 tiles)
        transpose_tile(W1, WT1, DDIM, FDIM, isbf, e, bx, by, tile);
        return;
    }
    b -= TW1;
    if (b < NORMB) {   // ---- normalize x to bf16
        size_t i = ((size_t)b * 256 + threadIdx.x) * 8;
        if (isbf) {
            *(ushort8*)(xb + i) = *(const ushort8*)((const u16*)x + i);
        } else {
            const float* xf = (const float*)x + i;
            floatx4 a = *(const floatx4*)xf;
            floatx4 bb = *(const floatx4*)(xf + 4);
            ushort8 o;
#pragma unroll
            for (int l = 0; l < 4; ++l) { o[l] = f2b(a[l]); o[4 + l] = f2b(bb[l]); }
            *(ushort8*)(xb + i) = o;
        }
        return;
    }
    b -= NORMB;
    // ---- router: 4 tokens per block, one wave per token
    int t = b * 4 + (threadIdx.x >> 6);
    int lane = threadIdx.x & 63;
    float acc[NEXP];
#pragma unroll
    for (int e = 0; e < NEXP; ++e) acc[e] = 0.f;
    if (isbf) {
        const u16* xrow = (const u16*)x + (size_t)t * DDIM;
        const u16* wr = (const u16*)wrr;
        for (int j = 0; j < DDIM / 64; ++j) {
            int d = lane + j * 64;
            float xv = b2f(xrow[d]);
            ushort8 wv = *(const ushort8*)(wr + (size_t)d * NEXP);
#pragma unroll
            for (int e = 0; e < NEXP; ++e) acc[e] += xv * b2f(wv[e]);
        }
    } else {
        const float* xrow = (const float*)x + (size_t)t * DDIM;
        const float* wr = (const float*)wrr;
        for (int j = 0; j < DDIM / 64; ++j) {
            int d = lane + j * 64;
            float xv = xrow[d];
            floatx4 w0 = *(const floatx4*)(wr + (size_t)d * NEXP);
            floatx4 w1 = *(const floatx4*)(wr + (size_t)d * NEXP + 4);
#pragma unroll
            for (int l = 0; l < 4; ++l) { acc[l] += xv * w0[l]; acc[4 + l] += xv * w1[l]; }
        }
    }
#pragma unroll
    for (int off = 32; off > 0; off >>= 1)
#pragma unroll
        for (int e = 0; e < NEXP; ++e) acc[e] += __shfl_xor(acc[e], off, 64);
    if (lane == 0) {
        float v[NEXP];
#pragma unroll
        for (int e = 0; e < NEXP; ++e) v[e] = isbf ? bf16r(acc[e]) : acc[e];
        int e0 = 0;
        for (int e = 1; e < NEXP; ++e) if (v[e] > v[e0]) e0 = e;   // lowest idx wins ties
        int e1 = (e0 == 0) ? 1 : 0;
        for (int e = 0; e < NEXP; ++e) if (e != e0 && v[e] > v[e1]) e1 = e;
        float dlt = expf(v[e1] - v[e0]);           // <= 1
        float w0 = 1.f / (1.f + dlt);
        float w1 = dlt / (1.f + dlt);
        tok_e[2 * t] = e0; tok_e[2 * t + 1] = e1;
        tok_w[2 * t]     = isbf ? bf16r(w0) : w0;
        tok_w[2 * t + 1] = isbf ? bf16r(w1) : w1;
        atomicAdd(&counts[e0], 1);
        atomicAdd(&counts[e1], 1);
    }
}

// ---------------- per-expert offsets, 128-aligned segments --------------------
__global__ void offsets_kernel(const int* counts, int* offs) {
    if (threadIdx.x == 0) {
        int o = 0; offs[0] = 0;
        for (int e = 0; e < NEXP; ++e) { o += ((counts[e] + 127) & ~127); offs[e + 1] = o; }
    }
}

// ---------------- scatter tokens into expert-sorted row list ------------------
__global__ __launch_bounds__(256) void scatter_kernel(const int* __restrict__ tok_e,
        const float* __restrict__ tok_w, const int* __restrict__ offs, int* cursor,
        int* __restrict__ row_token, float* __restrict__ row_weight,
        int* __restrict__ tok_rows) {
    int t = blockIdx.x * 256 + threadIdx.x;
    if (t >= NTOK) return;
#pragma unroll
    for (int k = 0; k < 2; ++k) {
        int e = tok_e[2 * t + k];
        int pos = offs[e] + atomicAdd(&cursor[e], 1);
        row_token[pos] = t;
        row_weight[pos] = tok_w[2 * t + k];
        tok_rows[2 * t + k] = pos;
    }
}

// ---------------- standalone transpose (fallback path only) -------------------
__global__ __launch_bounds__(256) void transpose_kernel(const void* __restrict__ src,
        u16* __restrict__ dst, int R, int C, const int* __restrict__ flag) {
    __shared__ u16 tile[64 * 66];
    transpose_tile(src, dst, R, C, *flag, blockIdx.z, blockIdx.x, blockIdx.y, tile);
}

// ---------------- ring-pipelined GEMM body ------------------------------------
// BM=128, BN=128, BK=32. 256 threads = 4 waves (2m x 2n), wave tile 64x64.
// 3-slot LDS ring (48 KB) -> 3 blocks/CU = 12 waves/CU (the TLP round-0 had and
// rounds 1-2 lost). Stage t+2 while computing t; steady s_waitcnt vmcnt(4)
// (one slot = 4 loads), drain only at the last step. K-granule XOR swizzle via
// pre-swizzled GLOBAL source (linear LDS dest) -> conflict-free ds_read_b128
// (0 conflicts measured in rounds 1-2). n-outer + bijective XCD chunk swizzle.
// K-accumulation order identical to prior rounds -> bit-identical results.
template<int K, int N, bool GATHER, bool GELU_OUT>
__device__ __forceinline__ void gemm_body(int g, int ngw, const u16* __restrict__ A,
        const u16* __restrict__ Bw, u16* __restrict__ C,
        const int* __restrict__ row_token, const int* __restrict__ offs,
        u16* __restrict__ sm /* 3*8192 u16 */) {
    constexpr int NT = K / 32;
    const int tid = threadIdx.x;
    g = (g & 7) * (ngw >> 3) + (g >> 3);           // XCD chunk swizzle (ngw % 8 == 0)
    const int m0 = (g % MTILES) * 128;             // n-outer: same-XCD blocks share n
    const int n0 = (g / MTILES) * 128;
    if (m0 >= offs[NEXP]) return;
    int e = 0;
#pragma unroll
    for (int i = 1; i <= NEXP; ++i) e += (m0 >= offs[i]) ? 1 : 0;
    if (e > 7) e = 7;
    const u16* Bb = Bw + (size_t)e * (size_t)N * K;

    // staging: thread covers tile row (half*64 + tid/4), granule tid&3; source
    // col pre-swizzled by ((tid&3) ^ ((row>>1)&3))*8 (64-row offsets invariant).
    const int rr = tid >> 2;
    const int cshift = ((tid & 3) ^ ((rr >> 1) & 3)) * 8;
    const u16 *pA0, *pA1;
    if constexpr (GATHER) {
        pA0 = A + (size_t)row_token[m0 + rr] * K + cshift;
        pA1 = A + (size_t)row_token[m0 + 64 + rr] * K + cshift;
    } else {
        pA0 = A + (size_t)(m0 + rr) * K + cshift;
        pA1 = pA0 + (size_t)64 * K;
    }
    const u16* pB0 = Bb + (size_t)(n0 + rr) * K + cshift;
    const u16* pB1 = pB0 + (size_t)64 * K;

    // fragment read offsets (bytes), XOR matches staged layout (invariant under
    // +16-row frag steps).
    const int lane = tid & 63;
    const int w = tid >> 6;
    const int wm = (w >> 1) * 64;
    const int wn = (w & 1) * 64;
    const int lm = lane & 15;
    const int kb = (lane >> 4) * 16;
    const int rA = wm + lm;
    const int aoff = rA * 64 + (kb ^ (((rA >> 1) & 3) << 4));
    const int rB = wn + lm;
    const int boff = 8192 + rB * 64 + (kb ^ (((rB >> 1) & 3) << 4));

    floatx4 acc[4][4];
#pragma unroll
    for (int i = 0; i < 4; ++i)
#pragma unroll
        for (int j = 0; j < 4; ++j) acc[i][j] = (floatx4){0.f, 0.f, 0.f, 0.f};

    auto stage = [&](int t, int slot) {
        u16* d = sm + slot * 8192;
        const int ko = t * 32;
        async16(pA0 + ko, d + tid * 8);
        async16(pA1 + ko, d + 2048 + tid * 8);
        async16(pB0 + ko, d + 4096 + tid * 8);
        async16(pB1 + ko, d + 6144 + tid * 8);
    };

    stage(0, 0);
    stage(1, 1);

    int rs = 0;   // slot holding tile t
    for (int t = 0; t < NT; ++t) {
        if (t < NT - 1) waitbar<4>(); else waitbar<0>();
        const char* Ls = (const char*)(sm + rs * 8192);
        short8 bf[4], af[4];
#pragma unroll
        for (int j = 0; j < 4; ++j) bf[j] = *(const short8*)(Ls + boff + j * 1024);
#pragma unroll
        for (int i = 0; i < 4; ++i) af[i] = *(const short8*)(Ls + aoff + i * 1024);
        if (t + 2 < NT) stage(t + 2, rs == 0 ? 2 : rs - 1);   // slot (t+2)%3
        __builtin_amdgcn_s_setprio(1);
#pragma unroll
        for (int i = 0; i < 4; ++i)
#pragma unroll
            for (int j = 0; j < 4; ++j)
                acc[i][j] = __builtin_amdgcn_mfma_f32_16x16x32_bf16(af[i], bf[j], acc[i][j], 0, 0, 0);
        __builtin_amdgcn_s_setprio(0);
        rs = (rs == 2) ? 0 : rs + 1;
    }

    const int rq = (lane >> 4) * 4;
#pragma unroll
    for (int i = 0; i < 4; ++i)
#pragma unroll
        for (int j = 0; j < 4; ++j)
#pragma unroll
            for (int r = 0; r < 4; ++r) {
                int row = m0 + wm + i * 16 + rq + r;
                int col = n0 + wn + j * 16 + lm;
                float v;
                if constexpr (GELU_OUT) {
                    float hb = bf16r(acc[i][j][r]);   // ref rounds matmul to bf16 first
                    v = 0.5f * hb * (1.f + erff(hb * 0.70710678118654752f));
                } else {
                    v = acc[i][j][r];
                }
                C[(size_t)row * N + col] = f2b(v);
            }
}

// gemm1 fused with the W2 transpose: 1 gemm block per 4 transpose blocks,
// interleaved so the BW-bound transpose fills gemm1's idle memory pipes.
// W2T completion before gemm2 is guaranteed by the kernel boundary.
__global__ __launch_bounds__(256, 3) void gemm1_fused(const u16* __restrict__ xb,
        const u16* __restrict__ WT1, u16* __restrict__ H,
        const int* __restrict__ row_token, const int* __restrict__ offs,
        const void* __restrict__ W2, u16* __restrict__ W2T,
        const int* __restrict__ flag, int tblocks) {
    __shared__ u16 sm[3 * 8192];
    int b = blockIdx.x;
    int g = -1, tt = -1;
    if (tblocks == 0) {
        g = b;
    } else if (b < 4 * G1BLK) {
        if ((b & 3) == 0) g = b >> 2;
        else tt = 3 * (b >> 2) + (b & 3) - 1;
    } else {
        tt = 3 * G1BLK + (b - 4 * G1BLK);
    }
    if (tt >= 0) {   // ---- W2 [F][D] -> W2T [D][F], per expert
        int e = tt >> 10, rem = tt & 1023;
        int bx = rem & 15, by = rem >> 4;   // C=DDIM (16 tiles), R=FDIM (64 tiles)
        transpose_tile(W2, W2T, FDIM, DDIM, *flag, e, bx, by, sm);
        return;
    }
    gemm_body<DDIM, FDIM, true, true>(g, G1BLK, xb, WT1, H, row_token, offs, sm);
}

__global__ __launch_bounds__(256, 3) void gemm2_ring(const u16* __restrict__ H,
        const u16* __restrict__ W2T, u16* __restrict__ Y,
        const int* __restrict__ offs) {
    __shared__ u16 sm[3 * 8192];
    gemm_body<FDIM, DDIM, false, false>(blockIdx.x, G2BLK, H, W2T, Y, nullptr, offs, sm);
}

// ---------------- combine: out[t] = w0*Y[r0] + w1*Y[r1] (fp32 sum) ------------
__global__ __launch_bounds__(256) void combine_kernel(const u16* __restrict__ Y,
        const int* __restrict__ tok_rows, const float* __restrict__ row_weight,
        const int* __restrict__ flag, void* __restrict__ out) {
    int c = blockIdx.x * 256 + threadIdx.x;
    int t = c >> 7;             // D/8 = 128 chunks per token
    int d0 = (c & 127) * 8;
    int r0 = tok_rows[2 * t], r1 = tok_rows[2 * t + 1];
    float w0 = row_weight[r0], w1 = row_weight[r1];
    ushort8 y0 = *(const ushort8*)(Y + (size_t)r0 * DDIM + d0);
    ushort8 y1 = *(const ushort8*)(Y + (size_t)r1 * DDIM + d0);
    float o[8];
#pragma unroll
    for (int l = 0; l < 8; ++l) o[l] = w0 * b2f(y0[l]) + w1 * b2f(y1[l]);
    if (*flag) {
        ushort8 ob;
#pragma unroll
        for (int l = 0; l < 8; ++l) ob[l] = f2b(o[l]);
        *(ushort8*)((u16*)out + (size_t)t * DDIM + d0) = ob;
    } else {
        floatx4 a, b;
#pragma unroll
        for (int l = 0; l < 4; ++l) { a[l] = o[l]; b[l] = o[4 + l]; }
        float* of = (float*)out + (size_t)t * DDIM + d0;
        *(floatx4*)of = a;
        *(floatx4*)(of + 4) = b;
    }
}

extern "C" void kernel_launch(void* const* d_in, const int* in_sizes, int n_in,
                              void* d_out, int out_size, void* d_ws, size_t ws_size,
                              hipStream_t stream) {
    const void* x  = d_in[0];
    const void* Wr = d_in[1];
    const void* W1 = d_in[2];
    const void* W2 = d_in[3];

    char* ws = (char*)d_ws;
    size_t off = 0;
    u16* xb  = (u16*)(ws + off); off += (size_t)NTOK * DDIM * 2;            // 8.4 MB
    u16* H   = (u16*)(ws + off); off += (size_t)ROWS_PAD * FDIM * 2;        // 75.5 MB
    u16* WT1 = (u16*)(ws + off); off += (size_t)NEXP * DDIM * FDIM * 2;     // 67 MB
    u16* Y   = (u16*)(ws + off); off += (size_t)ROWS_PAD * DDIM * 2;        // 18.9 MB
    int*   row_token  = (int*)(ws + off); off += ROWS_PAD * 4;
    float* row_weight = (float*)(ws + off); off += ROWS_PAD * 4;
    int*   tok_e    = (int*)(ws + off); off += NTOK * 2 * 4;
    float* tok_w    = (float*)(ws + off); off += NTOK * 2 * 4;
    int*   tok_rows = (int*)(ws + off); off += NTOK * 2 * 4;
    int*   counts16 = (int*)(ws + off); off += 16 * 4;   // counts[8] + cursor[8]
    int*   offs     = (int*)(ws + off); off += 16 * 4;
    int*   flag     = (int*)(ws + off); off += 64;
    size_t off_small = off;
    u16* W2Tsep = (u16*)(ws + off); off += (size_t)NEXP * DDIM * FDIM * 2;  // +67 MB
    const bool bigws = (ws_size >= off);
    u16* W2T = bigws ? W2Tsep : WT1;   // fallback: reuse WT1 serially
    (void)in_sizes; (void)n_in; (void)out_size; (void)off_small;

    hipLaunchKernelGGL(init_probe_kernel, dim3(ROWS_PAD / 256), dim3(256), 0, stream,
                       (const u16*)Wr, flag, row_token, row_weight, counts16);
    // W1 transpose + x normalize + router, one launch (all independent)
    hipLaunchKernelGGL(prep_kernel, dim3(TW1 + NORMB + ROUTB), dim3(256), 0, stream,
                       W1, WT1, x, xb, Wr, flag, tok_e, tok_w, counts16);
    hipLaunchKernelGGL(offsets_kernel, dim3(1), dim3(64), 0, stream, counts16, offs);
    hipLaunchKernelGGL(scatter_kernel, dim3(16), dim3(256), 0, stream,
                       tok_e, tok_w, offs, counts16 + 8, row_token, row_weight, tok_rows);
    if (bigws) {
        // gemm1 with W2 transpose blocks interleaved (1 gemm : 3 transpose, tail pure-transpose)
        hipLaunchKernelGGL(gemm1_fused, dim3(4 * G1BLK + (TW2 - 3 * G1BLK)), dim3(256), 0, stream,
                           xb, WT1, H, row_token, offs, W2, W2T, flag, TW2);
    } else {
        hipLaunchKernelGGL(gemm1_fused, dim3(G1BLK), dim3(256), 0, stream,
                           xb, WT1, H, row_token, offs, W2, W2T, flag, 0);
        hipLaunchKernelGGL(transpose_kernel, dim3(DDIM / 64, FDIM / 64, NEXP), dim3(256), 0, stream,
                           W2, W2T, FDIM, DDIM, flag);
    }
    hipLaunchKernelGGL(gemm2_ring, dim3(G2BLK), dim3(256), 0, stream,
                       H, W2T, Y, offs);
    hipLaunchKernelGGL(combine_kernel, dim3(NTOK * DDIM / 8 / 256), dim3(256), 0, stream,
                       Y, tok_rows, row_weight, flag, d_out);
}

// Round 4
// 736.358 us; speedup vs baseline: 1.2358x; 1.2358x over previous
//
#include <hip/hip_runtime.h>
#include <math.h>

typedef unsigned short u16;
typedef __attribute__((ext_vector_type(8))) short short8;
typedef __attribute__((ext_vector_type(8))) unsigned short ushort8;
typedef __attribute__((ext_vector_type(4))) float floatx4;

#define NTOK 4096
#define DDIM 1024
#define FDIM 4096
#define NEXP 8
#define ROWS_PAD 10240   // 8192 + 8*256 worst-case per-expert 256-padding
#define MT 40            // ROWS_PAD / 256
#define G1BLK ((FDIM / 256) * MT)              // 640
#define G2BLK ((DDIM / 256) * MT)              // 160
#define TW1 ((FDIM / 64) * (DDIM / 64) * NEXP) // 8192 W1-transpose tiles
#define NORMB (NTOK * DDIM / 8 / 256)          // 2048
#define ROUTB (NTOK / 4)                       // 1024

// ---------- bf16 <-> f32 (raw bits, RNE) ----------
__device__ __forceinline__ float b2f(u16 u) {
    union { unsigned u32; float f; } v; v.u32 = ((unsigned)u) << 16; return v.f;
}
__device__ __forceinline__ u16 f2b(float f) {
    union { float f; unsigned u; } v; v.f = f;
    unsigned u = v.u;
    return (u16)((u + 0x7fffu + ((u >> 16) & 1u)) >> 16);
}
__device__ __forceinline__ float bf16r(float f) { return b2f(f2b(f)); }

// async global->LDS, 16B per lane. LDS dest must be wave-uniform base + lane*16.
__device__ __forceinline__ void async16(const u16* g, u16* l) {
    __builtin_amdgcn_global_load_lds((const __attribute__((address_space(1))) void*)g,
                                     (__attribute__((address_space(3))) void*)l,
                                     16, 0, 0);
}

// ---------------- init + dtype probe ------------------------------------------
__global__ __launch_bounds__(256) void init_probe_kernel(const u16* __restrict__ wr,
        int* __restrict__ flag, int* __restrict__ row_token,
        float* __restrict__ row_weight, int* __restrict__ counts16) {
    int i = blockIdx.x * 256 + threadIdx.x;
    if (i < ROWS_PAD) { row_token[i] = 0; row_weight[i] = 0.f; }
    if (i < 16) counts16[i] = 0;   // counts[8] + cursor[8]
    if (blockIdx.x == 0) {
        __shared__ int cnt;
        if (threadIdx.x == 0) cnt = 0;
        __syncthreads();
        int c = 0;
        for (int k = threadIdx.x; k < 8192; k += 256) {
            int e = (wr[k] >> 7) & 0xFF;
            c += (e >= 90 && e <= 130) ? 1 : 0;
        }
        atomicAdd(&cnt, c);
        __syncthreads();
        if (threadIdx.x == 0) *flag = (cnt >= 7400) ? 1 : 0;   // 1 = bf16
    }
}

// ---------------- 64x64 transpose tile (256 threads), device-side -------------
__device__ __forceinline__ void transpose_tile(const void* __restrict__ src,
        u16* __restrict__ dst, int R, int C, int isbf, int e, int bx, int by,
        u16* tile /* 64*66 u16 scratch */) {
    size_t eoff = (size_t)e * R * C;
    int bc = bx * 64;
    int br = by * 64;
    int tid = threadIdx.x;
#pragma unroll
    for (int c = tid; c < 512; c += 256) {
        int r = c >> 3, cc = (c & 7) * 8;
        if (isbf) {
            ushort8 v = *(const ushort8*)((const u16*)src + eoff + (size_t)(br + r) * C + bc + cc);
#pragma unroll
            for (int l = 0; l < 8; ++l) tile[r * 66 + cc + l] = v[l];
        } else {
            const float* s = (const float*)src + eoff + (size_t)(br + r) * C + bc + cc;
            floatx4 a = *(const floatx4*)s;
            floatx4 b = *(const floatx4*)(s + 4);
#pragma unroll
            for (int l = 0; l < 4; ++l) { tile[r * 66 + cc + l] = f2b(a[l]); tile[r * 66 + cc + 4 + l] = f2b(b[l]); }
        }
    }
    __syncthreads();
#pragma unroll
    for (int c = tid; c < 512; c += 256) {
        int i = c >> 3, jj = (c & 7) * 8;
        ushort8 o;
#pragma unroll
        for (int l = 0; l < 8; ++l) o[l] = tile[(jj + l) * 66 + i];
        *(ushort8*)(dst + eoff + (size_t)(bc + i) * R + br + jj) = o;
    }
}

// ---------------- prep: W1 transpose + normx + router in one launch -----------
__global__ __launch_bounds__(256) void prep_kernel(const void* __restrict__ W1,
        u16* __restrict__ WT1, const void* __restrict__ x, u16* __restrict__ xb,
        const void* __restrict__ wrr, const int* __restrict__ flag,
        int* __restrict__ tok_e, float* __restrict__ tok_w, int* __restrict__ counts) {
    __shared__ u16 tile[64 * 66];
    int b = blockIdx.x;
    const int isbf = *flag;
    if (b < TW1) {   // ---- W1 [D][F] -> WT1 [F][D], per expert
        int e = b >> 10, rem = b & 1023;
        int bx = rem & 63, by = rem >> 6;   // C=FDIM (64 tiles), R=DDIM (16 tiles)
        transpose_tile(W1, WT1, DDIM, FDIM, isbf, e, bx, by, tile);
        return;
    }
    b -= TW1;
    if (b < NORMB) {   // ---- normalize x to bf16
        size_t i = ((size_t)b * 256 + threadIdx.x) * 8;
        if (isbf) {
            *(ushort8*)(xb + i) = *(const ushort8*)((const u16*)x + i);
        } else {
            const float* xf = (const float*)x + i;
            floatx4 a = *(const floatx4*)xf;
            floatx4 bb = *(const floatx4*)(xf + 4);
            ushort8 o;
#pragma unroll
            for (int l = 0; l < 4; ++l) { o[l] = f2b(a[l]); o[4 + l] = f2b(bb[l]); }
            *(ushort8*)(xb + i) = o;
        }
        return;
    }
    b -= NORMB;
    // ---- router: 4 tokens per block, one wave per token
    int t = b * 4 + (threadIdx.x >> 6);
    int lane = threadIdx.x & 63;
    float acc[NEXP];
#pragma unroll
    for (int e = 0; e < NEXP; ++e) acc[e] = 0.f;
    if (isbf) {
        const u16* xrow = (const u16*)x + (size_t)t * DDIM;
        const u16* wr = (const u16*)wrr;
        for (int j = 0; j < DDIM / 64; ++j) {
            int d = lane + j * 64;
            float xv = b2f(xrow[d]);
            ushort8 wv = *(const ushort8*)(wr + (size_t)d * NEXP);
#pragma unroll
            for (int e = 0; e < NEXP; ++e) acc[e] += xv * b2f(wv[e]);
        }
    } else {
        const float* xrow = (const float*)x + (size_t)t * DDIM;
        const float* wr = (const float*)wrr;
        for (int j = 0; j < DDIM / 64; ++j) {
            int d = lane + j * 64;
            float xv = xrow[d];
            floatx4 w0 = *(const floatx4*)(wr + (size_t)d * NEXP);
            floatx4 w1 = *(const floatx4*)(wr + (size_t)d * NEXP + 4);
#pragma unroll
            for (int l = 0; l < 4; ++l) { acc[l] += xv * w0[l]; acc[4 + l] += xv * w1[l]; }
        }
    }
#pragma unroll
    for (int off = 32; off > 0; off >>= 1)
#pragma unroll
        for (int e = 0; e < NEXP; ++e) acc[e] += __shfl_xor(acc[e], off, 64);
    if (lane == 0) {
        float v[NEXP];
#pragma unroll
        for (int e = 0; e < NEXP; ++e) v[e] = isbf ? bf16r(acc[e]) : acc[e];
        int e0 = 0;
        for (int e = 1; e < NEXP; ++e) if (v[e] > v[e0]) e0 = e;   // lowest idx wins ties
        int e1 = (e0 == 0) ? 1 : 0;
        for (int e = 0; e < NEXP; ++e) if (e != e0 && v[e] > v[e1]) e1 = e;
        float dlt = expf(v[e1] - v[e0]);           // <= 1
        float w0 = 1.f / (1.f + dlt);
        float w1 = dlt / (1.f + dlt);
        tok_e[2 * t] = e0; tok_e[2 * t + 1] = e1;
        tok_w[2 * t]     = isbf ? bf16r(w0) : w0;
        tok_w[2 * t + 1] = isbf ? bf16r(w1) : w1;
        atomicAdd(&counts[e0], 1);
        atomicAdd(&counts[e1], 1);
    }
}

// ---------------- per-expert offsets, 256-aligned segments --------------------
__global__ void offsets_kernel(const int* counts, int* offs) {
    if (threadIdx.x == 0) {
        int o = 0; offs[0] = 0;
        for (int e = 0; e < NEXP; ++e) { o += ((counts[e] + 255) & ~255); offs[e + 1] = o; }
    }
}

// ---------------- scatter tokens into expert-sorted row list ------------------
__global__ __launch_bounds__(256) void scatter_kernel(const int* __restrict__ tok_e,
        const float* __restrict__ tok_w, const int* __restrict__ offs, int* cursor,
        int* __restrict__ row_token, float* __restrict__ row_weight,
        int* __restrict__ tok_rows) {
    int t = blockIdx.x * 256 + threadIdx.x;
    if (t >= NTOK) return;
#pragma unroll
    for (int k = 0; k < 2; ++k) {
        int e = tok_e[2 * t + k];
        int pos = offs[e] + atomicAdd(&cursor[e], 1);
        row_token[pos] = t;
        row_weight[pos] = tok_w[2 * t + k];
        tok_rows[2 * t + k] = pos;
    }
}

// ---------------- standalone transpose ----------------------------------------
__global__ __launch_bounds__(256) void transpose_kernel(const void* __restrict__ src,
        u16* __restrict__ dst, int R, int C, const int* __restrict__ flag) {
    __shared__ u16 tile[64 * 66];
    transpose_tile(src, dst, R, C, *flag, blockIdx.z, blockIdx.x, blockIdx.y, tile);
}

// ---------------- 8-phase 256x256 GEMM (m201-template port) -------------------
// 512 threads = 8 waves (2m x 4n). BK=64, 2 LDS buffers x (A,B) x 2 halves x
// [128 rows][64 cols] = 128 KB. Per K-tile: 4 phases, one block-level C-quadrant
// (QM,QN) each; phase = {12 ds_read_b128, stage 1 half-tile of tile t+1 (2
// global_load_lds), barrier, setprio+16 MFMA, vmcnt(4), barrier}. Stage order
// A0,B0,B1,A1 -> per-phase vmcnt(4) lands each half-tile one phase before its
// first read (4-6 loads in flight, never drained mid-loop). Granule-XOR swizzle
// applied on the GLOBAL source (linear LDS dest) and on ds_read addrs -> 2-way
// bank aliasing (free). K order identical to prior rounds -> bit-identical.
#define PHASE(QM, QN, SMTX, SH, LASTT) do {                                     \
    const u16* Ah = sm + buf + (QM) * 8192;                                     \
    const u16* Bh = sm + buf + 16384 + (QN) * 8192;                             \
    short8 af0[4], af1[4], bf0[2], bf1[2];                                      \
    _Pragma("unroll") for (int i_ = 0; i_ < 4; ++i_) {                          \
        af0[i_] = *(const short8*)(Ah + a_base + i_ * 1024 + ks0);              \
        af1[i_] = *(const short8*)(Ah + a_base + i_ * 1024 + ks1); }            \
    _Pragma("unroll") for (int j_ = 0; j_ < 2; ++j_) {                          \
        bf0[j_] = *(const short8*)(Bh + b_base + j_ * 1024 + ks0);              \
        bf1[j_] = *(const short8*)(Bh + b_base + j_ * 1024 + ks1); }            \
    if (st) stage(SMTX, SH, t + 1, nbuf);                                       \
    asm volatile("s_barrier" ::: "memory");                                     \
    __builtin_amdgcn_s_setprio(1);                                              \
    _Pragma("unroll") for (int i_ = 0; i_ < 4; ++i_)                            \
        _Pragma("unroll") for (int j_ = 0; j_ < 2; ++j_)                        \
            acc[QM][QN][i_][j_] = __builtin_amdgcn_mfma_f32_16x16x32_bf16(      \
                af0[i_], bf0[j_], acc[QM][QN][i_][j_], 0, 0, 0);                \
    _Pragma("unroll") for (int i_ = 0; i_ < 4; ++i_)                            \
        _Pragma("unroll") for (int j_ = 0; j_ < 2; ++j_)                        \
            acc[QM][QN][i_][j_] = __builtin_amdgcn_mfma_f32_16x16x32_bf16(      \
                af1[i_], bf1[j_], acc[QM][QN][i_][j_], 0, 0, 0);                \
    __builtin_amdgcn_s_setprio(0);                                              \
    if (LASTT) asm volatile("s_waitcnt vmcnt(0)" ::: "memory");                 \
    else       asm volatile("s_waitcnt vmcnt(4)" ::: "memory");                 \
    asm volatile("s_barrier" ::: "memory");                                     \
} while (0)

template<int K, int N, bool GATHER, bool GELU_OUT>
__device__ __forceinline__ void gemm8_body(const u16* __restrict__ A,
        const u16* __restrict__ Bw, u16* __restrict__ C,
        const int* __restrict__ row_token, const int* __restrict__ offs,
        u16* __restrict__ sm /* 65536 u16 = 128KB */, int nwg) {
    constexpr int NT = K / 64;
    const int tid = threadIdx.x;
    int g = blockIdx.x;
    g = (g & 7) * (nwg >> 3) + (g >> 3);           // XCD chunk swizzle (nwg%8==0)
    const int m0 = (g % MT) * 256;                 // m fast within XCD: share n-panel
    const int n0 = (g / MT) * 256;
    if (m0 >= offs[NEXP]) return;
    int e = 0;
#pragma unroll
    for (int i = 1; i <= NEXP; ++i) e += (m0 >= offs[i]) ? 1 : 0;
    if (e > 7) e = 7;
    const u16* Bb = Bw + (size_t)e * (size_t)N * K;

    // staging source pointers: thread covers row (h*128 + l*64 + tid/8) of the
    // tile, granule tid&7, source col pre-swizzled by ((tid&7)^(row&7))*8.
    const int srow = tid >> 3;                     // 0..63
    const int cshift = ((tid & 7) ^ (srow & 7)) * 8;
    const u16 *pA[2][2], *pB[2][2];
#pragma unroll
    for (int h = 0; h < 2; ++h)
#pragma unroll
        for (int l = 0; l < 2; ++l) {
            int r = h * 128 + l * 64 + srow;
            if constexpr (GATHER) pA[h][l] = A + (size_t)row_token[m0 + r] * K + cshift;
            else                  pA[h][l] = A + (size_t)(m0 + r) * K + cshift;
            pB[h][l] = Bb + (size_t)(n0 + r) * K + cshift;
        }

    // fragment read offsets (u16 units). Row stride 64 u16 (128B). Granule of
    // lane: (ks*4 + kg) ^ (lm&7), kg=lane>>4 -> split into low-bits XOR (base)
    // and ks-bit XOR (ks0/ks1 offsets).
    const int lane = tid & 63;
    const int wid = tid >> 6;
    const int wm = wid >> 2;           // 0..1
    const int wn = wid & 3;            // 0..3
    const int lm = lane & 15;
    const int kg = lane >> 4;          // 0..3
    const int xh = (lm >> 2) & 1;
    const int gbase = (kg ^ (lm & 3)) * 8;
    const int ks0 = xh * 32;
    const int ks1 = (1 ^ xh) * 32;
    const int a_base = (wm * 64 + lm) * 64 + gbase;
    const int b_base = (wn * 32 + lm) * 64 + gbase;

    floatx4 acc[2][2][4][2];
#pragma unroll
    for (int qm = 0; qm < 2; ++qm)
#pragma unroll
        for (int qn = 0; qn < 2; ++qn)
#pragma unroll
            for (int i = 0; i < 4; ++i)
#pragma unroll
                for (int j = 0; j < 2; ++j)
                    acc[qm][qn][i][j] = (floatx4){0.f, 0.f, 0.f, 0.f};

    auto stage = [&](int mtx, int h, int tile, int nb) {
        const u16* s0 = (mtx ? pB[h][0] : pA[h][0]) + tile * 64;
        const u16* s1 = (mtx ? pB[h][1] : pA[h][1]) + tile * 64;
        u16* d = sm + nb + mtx * 16384 + h * 8192 + tid * 8;
        async16(s0, d);
        async16(s1, d + 4096);
    };

    // prologue: tile 0 fully into buf0, drain, barrier
    stage(0, 0, 0, 0); stage(1, 0, 0, 0); stage(1, 1, 0, 0); stage(0, 1, 0, 0);
    asm volatile("s_waitcnt vmcnt(0)" ::: "memory");
    asm volatile("s_barrier" ::: "memory");

    for (int t = 0; t < NT; ++t) {
        const int buf  = (t & 1) << 15;   // u16 offset 32768
        const int nbuf = buf ^ 32768;
        const bool st = (t + 1 < NT);
        PHASE(0, 0, 0, 0, false);            // stage A h0 of t+1
        PHASE(0, 1, 1, 0, false);            // stage B h0
        PHASE(1, 0, 1, 1, false);            // stage B h1
        PHASE(1, 1, 0, 1, (t == NT - 2));    // stage A h1; pre-last: drain
    }

    const int rq = (lane >> 4) * 4;
#pragma unroll
    for (int qm = 0; qm < 2; ++qm)
#pragma unroll
        for (int qn = 0; qn < 2; ++qn)
#pragma unroll
            for (int i = 0; i < 4; ++i)
#pragma unroll
                for (int j = 0; j < 2; ++j)
#pragma unroll
                    for (int r = 0; r < 4; ++r) {
                        int row = m0 + qm * 128 + wm * 64 + i * 16 + rq + r;
                        int col = n0 + qn * 128 + wn * 32 + j * 16 + lm;
                        float v;
                        if constexpr (GELU_OUT) {
                            float hb = bf16r(acc[qm][qn][i][j][r]);   // ref rounds matmul first
                            v = 0.5f * hb * (1.f + erff(hb * 0.70710678118654752f));
                        } else {
                            v = acc[qm][qn][i][j][r];
                        }
                        C[(size_t)row * N + col] = f2b(v);
                    }
}

__global__ __launch_bounds__(512, 2) void gemm1_8p(const u16* __restrict__ A,
        const u16* __restrict__ Bw, u16* __restrict__ C,
        const int* __restrict__ row_token, const int* __restrict__ offs) {
    __shared__ u16 sm[65536];
    gemm8_body<DDIM, FDIM, true, true>(A, Bw, C, row_token, offs, sm, G1BLK);
}

__global__ __launch_bounds__(512, 2) void gemm2_8p(const u16* __restrict__ A,
        const u16* __restrict__ Bw, u16* __restrict__ C,
        const int* __restrict__ offs) {
    __shared__ u16 sm[65536];
    gemm8_body<FDIM, DDIM, false, false>(A, Bw, C, nullptr, offs, sm, G2BLK);
}

// ---------------- combine: out[t] = w0*Y[r0] + w1*Y[r1] (fp32 sum) ------------
__global__ __launch_bounds__(256) void combine_kernel(const u16* __restrict__ Y,
        const int* __restrict__ tok_rows, const float* __restrict__ row_weight,
        const int* __restrict__ flag, void* __restrict__ out) {
    int c = blockIdx.x * 256 + threadIdx.x;
    int t = c >> 7;             // D/8 = 128 chunks per token
    int d0 = (c & 127) * 8;
    int r0 = tok_rows[2 * t], r1 = tok_rows[2 * t + 1];
    float w0 = row_weight[r0], w1 = row_weight[r1];
    ushort8 y0 = *(const ushort8*)(Y + (size_t)r0 * DDIM + d0);
    ushort8 y1 = *(const ushort8*)(Y + (size_t)r1 * DDIM + d0);
    float o[8];
#pragma unroll
    for (int l = 0; l < 8; ++l) o[l] = w0 * b2f(y0[l]) + w1 * b2f(y1[l]);
    if (*flag) {
        ushort8 ob;
#pragma unroll
        for (int l = 0; l < 8; ++l) ob[l] = f2b(o[l]);
        *(ushort8*)((u16*)out + (size_t)t * DDIM + d0) = ob;
    } else {
        floatx4 a, b;
#pragma unroll
        for (int l = 0; l < 4; ++l) { a[l] = o[l]; b[l] = o[4 + l]; }
        float* of = (float*)out + (size_t)t * DDIM + d0;
        *(floatx4*)of = a;
        *(floatx4*)(of + 4) = b;
    }
}

extern "C" void kernel_launch(void* const* d_in, const int* in_sizes, int n_in,
                              void* d_out, int out_size, void* d_ws, size_t ws_size,
                              hipStream_t stream) {
    const void* x  = d_in[0];
    const void* Wr = d_in[1];
    const void* W1 = d_in[2];
    const void* W2 = d_in[3];

    char* ws = (char*)d_ws;
    size_t off = 0;
    u16* xb  = (u16*)(ws + off); off += (size_t)NTOK * DDIM * 2;            // 8.4 MB
    u16* H   = (u16*)(ws + off); off += (size_t)ROWS_PAD * FDIM * 2;        // 83.9 MB
    u16* WT1 = (u16*)(ws + off); off += (size_t)NEXP * DDIM * FDIM * 2;     // 67 MB
    u16* Y   = (u16*)(ws + off); off += (size_t)ROWS_PAD * DDIM * 2;        // 21 MB
    int*   row_token  = (int*)(ws + off); off += ROWS_PAD * 4;
    float* row_weight = (float*)(ws + off); off += ROWS_PAD * 4;
    int*   tok_e    = (int*)(ws + off); off += NTOK * 2 * 4;
    float* tok_w    = (float*)(ws + off); off += NTOK * 2 * 4;
    int*   tok_rows = (int*)(ws + off); off += NTOK * 2 * 4;
    int*   counts16 = (int*)(ws + off); off += 16 * 4;   // counts[8] + cursor[8]
    int*   offs     = (int*)(ws + off); off += 16 * 4;
    int*   flag     = (int*)(ws + off); off += 64;
    u16* W2Tsep = (u16*)(ws + off); off += (size_t)NEXP * DDIM * FDIM * 2;  // +67 MB
    const bool bigws = (ws_size >= off);
    u16* W2T = bigws ? W2Tsep : WT1;   // fallback: reuse WT1 after gemm1
    (void)in_sizes; (void)n_in; (void)out_size;

    hipLaunchKernelGGL(init_probe_kernel, dim3(ROWS_PAD / 256), dim3(256), 0, stream,
                       (const u16*)Wr, flag, row_token, row_weight, counts16);
    // W1 transpose + x normalize + router, one launch (all independent)
    hipLaunchKernelGGL(prep_kernel, dim3(TW1 + NORMB + ROUTB), dim3(256), 0, stream,
                       W1, WT1, x, xb, Wr, flag, tok_e, tok_w, counts16);
    hipLaunchKernelGGL(offsets_kernel, dim3(1), dim3(64), 0, stream, counts16, offs);
    hipLaunchKernelGGL(scatter_kernel, dim3(16), dim3(256), 0, stream,
                       tok_e, tok_w, offs, counts16 + 8, row_token, row_weight, tok_rows);
    if (bigws) {
        hipLaunchKernelGGL(transpose_kernel, dim3(DDIM / 64, FDIM / 64, NEXP), dim3(256), 0, stream,
                           W2, W2T, FDIM, DDIM, flag);   // [F][D] -> [D][F]
        hipLaunchKernelGGL(gemm1_8p, dim3(G1BLK), dim3(512), 0, stream,
                           xb, WT1, H, row_token, offs);
    } else {
        hipLaunchKernelGGL(gemm1_8p, dim3(G1BLK), dim3(512), 0, stream,
                           xb, WT1, H, row_token, offs);
        hipLaunchKernelGGL(transpose_kernel, dim3(DDIM / 64, FDIM / 64, NEXP), dim3(256), 0, stream,
                           W2, W2T, FDIM, DDIM, flag);
    }
    hipLaunchKernelGGL(gemm2_8p, dim3(G2BLK), dim3(512), 0, stream,
                       H, W2T, Y, offs);
    hipLaunchKernelGGL(combine_kernel, dim3(NTOK * DDIM / 8 / 256), dim3(256), 0, stream,
                       Y, tok_rows, row_weight, flag, d_out);
}